// Round 6
// baseline (293.742 us; speedup 1.0000x reference)
//
#include <hip/hip_runtime.h>
#include <hip/hip_bf16.h>

// Router: r[b,e] = || weights[e] @ x[b] ||_2
//   x: [8192, 4096] f32, weights: [16, 64, 4096] f32 -> out: [8192, 16] f32
//
// Round-6: LDS-byte reduction.  R2/R3/R5 all hit 83-104 µs at 0.5
// ds_read/MFMA (64x64 wave tiles) — LDS-read-bound.  New decomposition:
// 8 waves = (2M x 2N) output owners of 128x64 (0.375 reads/MFMA, the
// m201/HK ratio) x 2 K-groups (kg owns one 32-wide k-half of each BK=64
// tile; partial accs merged via LDS at the end).  One barrier + one
// counted vmcnt per K-tile; per-wave lgkmcnt(0) guards each MFMA cluster.
// Swizzle pair (both-sides) and C/D mapping unchanged (R1-R5 verified).

constexpr int Bdim = 8192;
constexpr int Ddim = 4096;
constexpr int Edim = 16;
constexpr int Ndim = 1024;

constexpr int BM = 256, BN = 128, BK = 64;
constexpr int NT  = Ddim / BK;        // 64 K-tiles
constexpr int ASZ = BM * BK * 2;      // 32 KiB per A buffer
constexpr int BSZ = BN * BK * 2;      // 16 KiB per B buffer

typedef __bf16 v8bf __attribute__((ext_vector_type(8)));
typedef float  v4f  __attribute__((ext_vector_type(4)));

// ---------------------------------------------------------------------------
// f32 -> bf16 RNE, pure integer; x and w ranges fused into one dispatch.
// ---------------------------------------------------------------------------
__device__ __forceinline__ unsigned rne2(unsigned lo, unsigned hi) {
  unsigned a = (lo + 0x7fffu + ((lo >> 16) & 1u)) >> 16;
  unsigned b = (hi + 0x7fffu + ((hi >> 16) & 1u)) & 0xffff0000u;
  return a | b;
}

__global__ void cvt_all(const uint4* __restrict__ x, const uint4* __restrict__ w,
                        uint2* __restrict__ xp, uint2* __restrict__ wp,
                        int n4x, int n4tot) {
  int i = blockIdx.x * blockDim.x + threadIdx.x;
  int stride = gridDim.x * blockDim.x;
  for (; i < n4tot; i += stride) {
    const uint4* src; uint2* dst; int j;
    if (i < n4x) { src = x; dst = xp; j = i; }
    else         { src = w; dst = wp; j = i - n4x; }
    uint4 v = src[j];
    uint2 r;
    r.x = rne2(v.x, v.y);
    r.y = rne2(v.z, v.w);
    dst[j] = r;
  }
}

// ---------------------------------------------------------------------------
// async global->LDS, 16B per lane; LDS dest is wave-uniform base + lane*16.
// ---------------------------------------------------------------------------
__device__ __forceinline__ void gload_lds16(const void* gsrc, void* ldst) {
  __builtin_amdgcn_global_load_lds(
      (const __attribute__((address_space(1))) unsigned int*)gsrc,
      (__attribute__((address_space(3))) unsigned int*)ldst, 16, 0, 0);
}

// ---------------------------------------------------------------------------
// GEMM + fused router epilogue.
//
// vmcnt ledger (6 loads/tile/wave, in-order retirement):
//   prologue: stage t0,t1 (12 out); vmcnt(6) -> t0 landed; barrier.
//   tile t:   2 phases {4 a-reads (+4 b-reads in ph0); 3 stage-loads of
//             t+2; lgkmcnt(0); 16 MFMA} — no intra-tile barriers.
//             end: vmcnt(6) [t+1 landed] ; s_barrier.
//   tail:     t=NT-2 -> vmcnt(0); t=NT-1 -> no wait.
// W-A-R: stage(t+2) clobbers tile t-1's buffer; every wave's t-1 reads
// are lgkm-drained before it passed the (t-1 -> t) barrier. R-A-W: reads
// of tile t follow the barrier at which every wave retired t's loads.
// ---------------------------------------------------------------------------
__global__ __launch_bounds__(512, 2)
void gemm_router(const __bf16* __restrict__ Xp,  // [8192][4096]
                 const __bf16* __restrict__ Wp,  // [1024][4096]
                 float* __restrict__ out) {      // [8192][16]
  __shared__ __align__(16) char As[3 * ASZ];  // 96 KiB
  __shared__ __align__(16) char Bs[3 * BSZ];  // 48 KiB

  const int bid = blockIdx.x;       // 256 blocks
  const int bm  = bid >> 3;         // 0..31
  const int bn  = bid & 7;          // 0..7
  const int tid  = threadIdx.x;
  const int lane = tid & 63;
  const int wid  = tid >> 6;        // 0..7
  const int wr   = (wid >> 1) & 1;  // output row half (128 rows)
  const int wc   = wid & 1;         // output col half (64 cols = 1 expert)
  const int kg   = wid >> 2;        // K-group: k-half of each BK tile
  const int l15  = lane & 15;
  const int lg   = lane >> 4;
  const int lr   = lane >> 3;       // row within 8-row chunk
  const int ss   = (lane & 7) ^ lr; // pre-swizzled source 16B-slot
  const int l7   = l15 & 7;

  // staging: A = 32 chunks of 8 rows (4/wave), B = 16 chunks (2/wave)
  const __bf16* gA[4]; char* dA[4];
#pragma unroll
  for (int c = 0; c < 4; ++c) {
    int ca = wid * 4 + c;
    gA[c] = Xp + (size_t)(bm * BM + ca * 8 + lr) * Ddim + ss * 8;
    dA[c] = As + ca * 1024;
  }
  const __bf16* gB[2]; char* dB[2];
#pragma unroll
  for (int c = 0; c < 2; ++c) {
    int cb = wid * 2 + c;
    gB[c] = Wp + (size_t)(bn * BN + cb * 8 + lr) * Ddim + ss * 8;
    dB[c] = Bs + cb * 1024;
  }

  v4f acc[8][4] = {};   // 128x64 per wave-pair; this wave: its k-half partial

  // prologue: tiles 0 and 1
#pragma unroll
  for (int c = 0; c < 4; ++c) gload_lds16(gA[c], dA[c]);
#pragma unroll
  for (int c = 0; c < 2; ++c) gload_lds16(gB[c], dB[c]);
#pragma unroll
  for (int c = 0; c < 4; ++c) gload_lds16(gA[c] + BK, dA[c] + ASZ);
#pragma unroll
  for (int c = 0; c < 2; ++c) gload_lds16(gB[c] + BK, dB[c] + BSZ);
  asm volatile("s_waitcnt vmcnt(6)" ::: "memory");
  __builtin_amdgcn_s_barrier();
  __builtin_amdgcn_sched_barrier(0);

  const int slot = ((kg << 2) + lg) ^ l7;  // this wave's swizzled 16B-slot
  int cur = 0;
  for (int t = 0; t < NT; ++t) {
    const char* Ab = As + cur * ASZ;
    const char* Bb = Bs + cur * BSZ;
    int nxt = cur + 2; if (nxt >= 3) nxt -= 3;   // == tile t-1's buffer
    const bool st = (t + 2 < NT);
    const int ko = (t + 2) * BK;

    v8bf b[4];
#pragma unroll
    for (int nf = 0; nf < 4; ++nf) {
      int col = (wc << 6) + (nf << 4) + l15;
      b[nf] = *(const v8bf*)(Bb + col * 128 + (slot << 4));
    }
#pragma unroll
    for (int mh = 0; mh < 2; ++mh) {
      v8bf a[4];
#pragma unroll
      for (int i = 0; i < 4; ++i) {
        int row = (wr << 7) + ((mh * 4 + i) << 4) + l15;
        a[i] = *(const v8bf*)(Ab + row * 128 + (slot << 4));
      }
      if (st) {
        if (mh == 0) {
          gload_lds16(gA[0] + ko, dA[0] + nxt * ASZ);
          gload_lds16(gA[1] + ko, dA[1] + nxt * ASZ);
          gload_lds16(gA[2] + ko, dA[2] + nxt * ASZ);
        } else {
          gload_lds16(gA[3] + ko, dA[3] + nxt * ASZ);
          gload_lds16(gB[0] + ko, dB[0] + nxt * BSZ);
          gload_lds16(gB[1] + ko, dB[1] + nxt * BSZ);
        }
      }
      asm volatile("s_waitcnt lgkmcnt(0)" ::: "memory");
      __builtin_amdgcn_sched_barrier(0);
      __builtin_amdgcn_s_setprio(1);
#pragma unroll
      for (int i = 0; i < 4; ++i)
#pragma unroll
        for (int nf = 0; nf < 4; ++nf)
          acc[mh * 4 + i][nf] = __builtin_amdgcn_mfma_f32_16x16x32_bf16(
              a[i], b[nf], acc[mh * 4 + i][nf], 0, 0, 0);
      __builtin_amdgcn_s_setprio(0);
    }

    if (t < NT - 2)       asm volatile("s_waitcnt vmcnt(6)" ::: "memory");
    else if (t == NT - 2) asm volatile("s_waitcnt vmcnt(0)" ::: "memory");
    __builtin_amdgcn_s_barrier();
    __builtin_amdgcn_sched_barrier(0);
    cur += 1; if (cur >= 3) cur -= 3;
  }

  // --- merge K-group partials: wave (wr,wc,kg=1) -> LDS -> kg=0 adds ---
  const int pair = wid & 3;
  float* mbase = (pair < 3) ? (float*)(As + pair * 32768) : (float*)Bs;
  if (kg == 1) {
#pragma unroll
    for (int mf = 0; mf < 8; ++mf)
#pragma unroll
      for (int nf = 0; nf < 4; ++nf)
        *(v4f*)(mbase + ((size_t)(mf * 4 + nf) * 64 + lane) * 4) = acc[mf][nf];
  }
  __syncthreads();

  if (kg == 0) {
#pragma unroll
    for (int mf = 0; mf < 8; ++mf)
#pragma unroll
      for (int nf = 0; nf < 4; ++nf)
        acc[mf][nf] += *(const v4f*)(mbase + ((size_t)(mf * 4 + nf) * 64 + lane) * 4);

    // --- fused epilogue: r[row,e] = sqrt( sum_{k<64} C[row, e*64+k]^2 ) ---
    // C/D layout (m89/m91): col = lane&15, row = (lane>>4)*4 + reg.
    const int e = (bn << 1) + wc;
#pragma unroll
    for (int mf = 0; mf < 8; ++mf) {
#pragma unroll
      for (int reg = 0; reg < 4; ++reg) {
        float t = 0.f;
#pragma unroll
        for (int nf = 0; nf < 4; ++nf) {
          float v = acc[mf][nf][reg];
          t = fmaf(v, v, t);
        }
        t += __shfl_xor(t, 1);
        t += __shfl_xor(t, 2);
        t += __shfl_xor(t, 4);
        t += __shfl_xor(t, 8);
        if (l15 == 0) {
          int row = (bm << 8) + (wr << 7) + (mf << 4) + (lg << 2) + reg;
          out[(size_t)row * Edim + e] = sqrtf(t);
        }
      }
    }
  }
}

// ---------------------------------------------------------------------------
// Fallback (ws too small): plain fp32, correct but slow.
// ---------------------------------------------------------------------------
__global__ void router_naive(const float* __restrict__ x,
                             const float* __restrict__ w,
                             float* __restrict__ out) {
  int b = blockIdx.x;
  __shared__ float xs[Ddim];
  for (int d = threadIdx.x; d < Ddim; d += 256) xs[d] = x[(size_t)b * Ddim + d];
  __syncthreads();
  int n0 = threadIdx.x * 4;
  const float* wrow = w + (size_t)n0 * Ddim;
  float acc[4] = {0.f, 0.f, 0.f, 0.f};
  for (int d = 0; d < Ddim; ++d) {
    float xv = xs[d];
#pragma unroll
    for (int j = 0; j < 4; ++j) acc[j] = fmaf(xv, wrow[(size_t)j * Ddim + d], acc[j]);
  }
  float p = acc[0] * acc[0] + acc[1] * acc[1] + acc[2] * acc[2] + acc[3] * acc[3];
  p += __shfl_xor(p, 1);
  p += __shfl_xor(p, 2);
  p += __shfl_xor(p, 4);
  p += __shfl_xor(p, 8);
  if ((threadIdx.x & 15) == 0)
    out[(size_t)b * Edim + (threadIdx.x >> 4)] = sqrtf(p);
}

extern "C" void kernel_launch(void* const* d_in, const int* in_sizes, int n_in,
                              void* d_out, int out_size, void* d_ws,
                              size_t ws_size, hipStream_t stream) {
  const float* x = (const float*)d_in[0];
  const float* w = (const float*)d_in[1];
  float* out = (float*)d_out;

  const size_t xp_elems = (size_t)Bdim * Ddim;   // 33.5M bf16 (67 MB)
  const size_t wp_elems = (size_t)Ndim * Ddim;   // 4.2M bf16 (8.4 MB)
  const size_t need = (xp_elems + wp_elems) * sizeof(__bf16);  // ~76 MB

  if (ws_size >= need) {
    __bf16* Xp = (__bf16*)d_ws;
    __bf16* Wp = Xp + xp_elems;
    const int n4x = Bdim * Ddim / 4;
    const int n4t = n4x + Ndim * Ddim / 4;
    cvt_all<<<2304, 256, 0, stream>>>((const uint4*)x, (const uint4*)w,
                                      (uint2*)Xp, (uint2*)Wp, n4x, n4t);
    gemm_router<<<(Bdim / BM) * (Ndim / BN), 512, 0, stream>>>(Xp, Wp, out);
  } else {
    router_naive<<<Bdim, 256, 0, stream>>>(x, w, out);
  }
}

// Round 7
// 276.889 us; speedup vs baseline: 1.0609x; 1.0609x over previous
//
#include <hip/hip_runtime.h>
#include <hip/hip_bf16.h>

// Router: r[b,e] = || weights[e] @ x[b] ||_2
//   x: [8192, 4096] f32, weights: [16, 64, 4096] f32 -> out: [8192, 16] f32
//
// Round-7: R6 kernel + XCD-topology fix.  R2/R5/R6 invariant (83-85 µs,
// FETCH 266 MB, 3.2 TB/s) diagnosed as L2-fill-BW bound: XCD = bid%8 = bn
// meant every XCD L2 fetched the ENTIRE 67 MB Xp (544 MB logical fill =
// 6.5 TB/s = fill ceiling).  New decode: bm = (bid&7)*4 + ((bid>>3)&3),
// bn = bid>>5 -> each XCD owns a contiguous 4-panel bm chunk for all bn:
// per-XCD fill 17 MB, total 131 MB (4x less).  Everything else identical
// to R6 (verified: 8 waves = 2Mx2N x 2 K-groups, 3 LDS buffers, one
// barrier + counted vmcnt(6) per tile, swizzle pair, C/D mapping).

constexpr int Bdim = 8192;
constexpr int Ddim = 4096;
constexpr int Edim = 16;
constexpr int Ndim = 1024;

constexpr int BM = 256, BN = 128, BK = 64;
constexpr int NT  = Ddim / BK;        // 64 K-tiles
constexpr int ASZ = BM * BK * 2;      // 32 KiB per A buffer
constexpr int BSZ = BN * BK * 2;      // 16 KiB per B buffer

typedef __bf16 v8bf __attribute__((ext_vector_type(8)));
typedef float  v4f  __attribute__((ext_vector_type(4)));

// ---------------------------------------------------------------------------
// f32 -> bf16 RNE, pure integer; x and w ranges fused into one dispatch.
// ---------------------------------------------------------------------------
__device__ __forceinline__ unsigned rne2(unsigned lo, unsigned hi) {
  unsigned a = (lo + 0x7fffu + ((lo >> 16) & 1u)) >> 16;
  unsigned b = (hi + 0x7fffu + ((hi >> 16) & 1u)) & 0xffff0000u;
  return a | b;
}

__global__ void cvt_all(const uint4* __restrict__ x, const uint4* __restrict__ w,
                        uint2* __restrict__ xp, uint2* __restrict__ wp,
                        int n4x, int n4tot) {
  int i = blockIdx.x * blockDim.x + threadIdx.x;
  int stride = gridDim.x * blockDim.x;
  for (; i < n4tot; i += stride) {
    const uint4* src; uint2* dst; int j;
    if (i < n4x) { src = x; dst = xp; j = i; }
    else         { src = w; dst = wp; j = i - n4x; }
    uint4 v = src[j];
    uint2 r;
    r.x = rne2(v.x, v.y);
    r.y = rne2(v.z, v.w);
    dst[j] = r;
  }
}

// ---------------------------------------------------------------------------
// async global->LDS, 16B per lane; LDS dest is wave-uniform base + lane*16.
// ---------------------------------------------------------------------------
__device__ __forceinline__ void gload_lds16(const void* gsrc, void* ldst) {
  __builtin_amdgcn_global_load_lds(
      (const __attribute__((address_space(1))) unsigned int*)gsrc,
      (__attribute__((address_space(3))) unsigned int*)ldst, 16, 0, 0);
}

// ---------------------------------------------------------------------------
// GEMM + fused router epilogue.  (Structure identical to R6 — see header.)
// ---------------------------------------------------------------------------
__global__ __launch_bounds__(512, 2)
void gemm_router(const __bf16* __restrict__ Xp,  // [8192][4096]
                 const __bf16* __restrict__ Wp,  // [1024][4096]
                 float* __restrict__ out) {      // [8192][16]
  __shared__ __align__(16) char As[3 * ASZ];  // 96 KiB
  __shared__ __align__(16) char Bs[3 * BSZ];  // 48 KiB

  const int bid = blockIdx.x;       // 256 blocks, XCD = bid % 8
  // XCD-local bm chunk: XCD j gets bm in [4j, 4j+4) for ALL bn.
  const int bm  = ((bid & 7) << 2) + ((bid >> 3) & 3);  // 0..31
  const int bn  = bid >> 5;                             // 0..7
  const int tid  = threadIdx.x;
  const int lane = tid & 63;
  const int wid  = tid >> 6;        // 0..7
  const int wr   = (wid >> 1) & 1;  // output row half (128 rows)
  const int wc   = wid & 1;         // output col half (64 cols = 1 expert)
  const int kg   = wid >> 2;        // K-group: k-half of each BK tile
  const int l15  = lane & 15;
  const int lg   = lane >> 4;
  const int lr   = lane >> 3;       // row within 8-row chunk
  const int ss   = (lane & 7) ^ lr; // pre-swizzled source 16B-slot
  const int l7   = l15 & 7;

  // staging: A = 32 chunks of 8 rows (4/wave), B = 16 chunks (2/wave)
  const __bf16* gA[4]; char* dA[4];
#pragma unroll
  for (int c = 0; c < 4; ++c) {
    int ca = wid * 4 + c;
    gA[c] = Xp + (size_t)(bm * BM + ca * 8 + lr) * Ddim + ss * 8;
    dA[c] = As + ca * 1024;
  }
  const __bf16* gB[2]; char* dB[2];
#pragma unroll
  for (int c = 0; c < 2; ++c) {
    int cb = wid * 2 + c;
    gB[c] = Wp + (size_t)(bn * BN + cb * 8 + lr) * Ddim + ss * 8;
    dB[c] = Bs + cb * 1024;
  }

  v4f acc[8][4] = {};   // this wave's k-half partial of a 128x64 tile

  // prologue: tiles 0 and 1
#pragma unroll
  for (int c = 0; c < 4; ++c) gload_lds16(gA[c], dA[c]);
#pragma unroll
  for (int c = 0; c < 2; ++c) gload_lds16(gB[c], dB[c]);
#pragma unroll
  for (int c = 0; c < 4; ++c) gload_lds16(gA[c] + BK, dA[c] + ASZ);
#pragma unroll
  for (int c = 0; c < 2; ++c) gload_lds16(gB[c] + BK, dB[c] + BSZ);
  asm volatile("s_waitcnt vmcnt(6)" ::: "memory");
  __builtin_amdgcn_s_barrier();
  __builtin_amdgcn_sched_barrier(0);

  const int slot = ((kg << 2) + lg) ^ l7;  // this wave's swizzled 16B-slot
  int cur = 0;
  for (int t = 0; t < NT; ++t) {
    const char* Ab = As + cur * ASZ;
    const char* Bb = Bs + cur * BSZ;
    int nxt = cur + 2; if (nxt >= 3) nxt -= 3;   // == tile t-1's buffer
    const bool st = (t + 2 < NT);
    const int ko = (t + 2) * BK;

    v8bf b[4];
#pragma unroll
    for (int nf = 0; nf < 4; ++nf) {
      int col = (wc << 6) + (nf << 4) + l15;
      b[nf] = *(const v8bf*)(Bb + col * 128 + (slot << 4));
    }
#pragma unroll
    for (int mh = 0; mh < 2; ++mh) {
      v8bf a[4];
#pragma unroll
      for (int i = 0; i < 4; ++i) {
        int row = (wr << 7) + ((mh * 4 + i) << 4) + l15;
        a[i] = *(const v8bf*)(Ab + row * 128 + (slot << 4));
      }
      if (st) {
        if (mh == 0) {
          gload_lds16(gA[0] + ko, dA[0] + nxt * ASZ);
          gload_lds16(gA[1] + ko, dA[1] + nxt * ASZ);
          gload_lds16(gA[2] + ko, dA[2] + nxt * ASZ);
        } else {
          gload_lds16(gA[3] + ko, dA[3] + nxt * ASZ);
          gload_lds16(gB[0] + ko, dB[0] + nxt * BSZ);
          gload_lds16(gB[1] + ko, dB[1] + nxt * BSZ);
        }
      }
      asm volatile("s_waitcnt lgkmcnt(0)" ::: "memory");
      __builtin_amdgcn_sched_barrier(0);
      __builtin_amdgcn_s_setprio(1);
#pragma unroll
      for (int i = 0; i < 4; ++i)
#pragma unroll
        for (int nf = 0; nf < 4; ++nf)
          acc[mh * 4 + i][nf] = __builtin_amdgcn_mfma_f32_16x16x32_bf16(
              a[i], b[nf], acc[mh * 4 + i][nf], 0, 0, 0);
      __builtin_amdgcn_s_setprio(0);
    }

    if (t < NT - 2)       asm volatile("s_waitcnt vmcnt(6)" ::: "memory");
    else if (t == NT - 2) asm volatile("s_waitcnt vmcnt(0)" ::: "memory");
    __builtin_amdgcn_s_barrier();
    __builtin_amdgcn_sched_barrier(0);
    cur += 1; if (cur >= 3) cur -= 3;
  }

  // --- merge K-group partials: wave (wr,wc,kg=1) -> LDS -> kg=0 adds ---
  const int pair = wid & 3;
  float* mbase = (pair < 3) ? (float*)(As + pair * 32768) : (float*)Bs;
  if (kg == 1) {
#pragma unroll
    for (int mf = 0; mf < 8; ++mf)
#pragma unroll
      for (int nf = 0; nf < 4; ++nf)
        *(v4f*)(mbase + ((size_t)(mf * 4 + nf) * 64 + lane) * 4) = acc[mf][nf];
  }
  __syncthreads();

  if (kg == 0) {
#pragma unroll
    for (int mf = 0; mf < 8; ++mf)
#pragma unroll
      for (int nf = 0; nf < 4; ++nf)
        acc[mf][nf] += *(const v4f*)(mbase + ((size_t)(mf * 4 + nf) * 64 + lane) * 4);

    // --- fused epilogue: r[row,e] = sqrt( sum_{k<64} C[row, e*64+k]^2 ) ---
    // C/D layout (m89/m91): col = lane&15, row = (lane>>4)*4 + reg.
    const int e = (bn << 1) + wc;
#pragma unroll
    for (int mf = 0; mf < 8; ++mf) {
#pragma unroll
      for (int reg = 0; reg < 4; ++reg) {
        float t = 0.f;
#pragma unroll
        for (int nf = 0; nf < 4; ++nf) {
          float v = acc[mf][nf][reg];
          t = fmaf(v, v, t);
        }
        t += __shfl_xor(t, 1);
        t += __shfl_xor(t, 2);
        t += __shfl_xor(t, 4);
        t += __shfl_xor(t, 8);
        if (l15 == 0) {
          int row = (bm << 8) + (wr << 7) + (mf << 4) + (lg << 2) + reg;
          out[(size_t)row * Edim + e] = sqrtf(t);
        }
      }
    }
  }
}

// ---------------------------------------------------------------------------
// Fallback (ws too small): plain fp32, correct but slow.
// ---------------------------------------------------------------------------
__global__ void router_naive(const float* __restrict__ x,
                             const float* __restrict__ w,
                             float* __restrict__ out) {
  int b = blockIdx.x;
  __shared__ float xs[Ddim];
  for (int d = threadIdx.x; d < Ddim; d += 256) xs[d] = x[(size_t)b * Ddim + d];
  __syncthreads();
  int n0 = threadIdx.x * 4;
  const float* wrow = w + (size_t)n0 * Ddim;
  float acc[4] = {0.f, 0.f, 0.f, 0.f};
  for (int d = 0; d < Ddim; ++d) {
    float xv = xs[d];
#pragma unroll
    for (int j = 0; j < 4; ++j) acc[j] = fmaf(xv, wrow[(size_t)j * Ddim + d], acc[j]);
  }
  float p = acc[0] * acc[0] + acc[1] * acc[1] + acc[2] * acc[2] + acc[3] * acc[3];
  p += __shfl_xor(p, 1);
  p += __shfl_xor(p, 2);
  p += __shfl_xor(p, 4);
  p += __shfl_xor(p, 8);
  if ((threadIdx.x & 15) == 0)
    out[(size_t)b * Edim + (threadIdx.x >> 4)] = sqrtf(p);
}

extern "C" void kernel_launch(void* const* d_in, const int* in_sizes, int n_in,
                              void* d_out, int out_size, void* d_ws,
                              size_t ws_size, hipStream_t stream) {
  const float* x = (const float*)d_in[0];
  const float* w = (const float*)d_in[1];
  float* out = (float*)d_out;

  const size_t xp_elems = (size_t)Bdim * Ddim;   // 33.5M bf16 (67 MB)
  const size_t wp_elems = (size_t)Ndim * Ddim;   // 4.2M bf16 (8.4 MB)
  const size_t need = (xp_elems + wp_elems) * sizeof(__bf16);  // ~76 MB

  if (ws_size >= need) {
    __bf16* Xp = (__bf16*)d_ws;
    __bf16* Wp = Xp + xp_elems;
    const int n4x = Bdim * Ddim / 4;
    const int n4t = n4x + Ndim * Ddim / 4;
    cvt_all<<<2304, 256, 0, stream>>>((const uint4*)x, (const uint4*)w,
                                      (uint2*)Xp, (uint2*)Wp, n4x, n4t);
    gemm_router<<<(Bdim / BM) * (Ndim / BN), 512, 0, stream>>>(Xp, Wp, out);
  } else {
    router_naive<<<Bdim, 256, 0, stream>>>(x, w, out);
  }
}